// Round 18
// baseline (72.822 us; speedup 1.0000x reference)
//
#include <hip/hip_runtime.h>
#include <math.h>

// V=4 views, N=8192 points, 6 directed chamfer terms (pair p rows=view pi, min over view pj)
#define VNUM   4
#define NPAIRS 6
#define BLK    256
#define QTILE  2048   // b-points per block (quarter of N)
#define CHUNK  1024   // b-points staged per LDS phase (32 KB)

using short8  = __attribute__((ext_vector_type(8)))  short;
using f32x16  = __attribute__((ext_vector_type(16))) float;

__device__ inline unsigned short f2bf(float x) {           // RNE to bf16
    unsigned u = __float_as_uint(x);
    return (unsigned short)((u + 0x7FFFu + ((u >> 16) & 1u)) >> 16);
}
__device__ inline float bf2f(unsigned short b) {
    return __uint_as_float(((unsigned)b) << 16);
}
__device__ inline unsigned pk(unsigned short lo, unsigned short hi) {
    return (unsigned)lo | ((unsigned)hi << 16);
}

// Kernel 1: world-transform, build K=16 bf16 fragments so that
// dot(Afrag[a], Bfrag[b]) = |a|^2 + |b|^2 - 2*(a_hi+a_lo).(b_hi+b_lo).
// Fragments only; minbuf/done/out are memset-initialized in-graph.
__global__ void setup_kernel(const float* __restrict__ pts,
                             const float* __restrict__ poses,
                             unsigned short* __restrict__ afr,
                             unsigned short* __restrict__ bfr, int N) {
    int idx = blockIdx.x * blockDim.x + threadIdx.x;
    if (idx >= VNUM * N) return;
    int v = idx / N;
    const float* P = poses + v * 16;                       // row-major 4x4
    float px = pts[idx*3+0], py = pts[idx*3+1], pz = pts[idx*3+2];
    float x = fmaf(P[0], px, fmaf(P[1], py, fmaf(P[2],  pz, P[3])));
    float y = fmaf(P[4], px, fmaf(P[5], py, fmaf(P[6],  pz, P[7])));
    float z = fmaf(P[8], px, fmaf(P[9], py, fmaf(P[10], pz, P[11])));
    float s = fmaf(x, x, fmaf(y, y, z * z));
    unsigned short xh = f2bf(x), yh = f2bf(y), zh = f2bf(z);
    unsigned short xl = f2bf(x - bf2f(xh));
    unsigned short yl = f2bf(y - bf2f(yh));
    unsigned short zl = f2bf(z - bf2f(zh));
    unsigned short sh = f2bf(s), sl = f2bf(s - bf2f(sh));
    const unsigned short one = 0x3F80u;
    // -2 * bf16 is exact (power-of-two scale)
    unsigned short bxh = f2bf(-2.0f * bf2f(xh)), byh = f2bf(-2.0f * bf2f(yh)),
                   bzh = f2bf(-2.0f * bf2f(zh));
    unsigned short bxl = f2bf(-2.0f * bf2f(xl)), byl = f2bf(-2.0f * bf2f(yl)),
                   bzl = f2bf(-2.0f * bf2f(zl));
    // A[0..15] = xh,yh,zh, xh,yh,zh, xl,yl,zl, sh,sl, one,one, xl,yl,zl
    uint4* A4 = (uint4*)(afr + (size_t)idx * 16);
    A4[0] = make_uint4(pk(xh,yh), pk(zh,xh), pk(yh,zh), pk(xl,yl));
    A4[1] = make_uint4(pk(zl,sh), pk(sl,one), pk(one,xl), pk(yl,zl));
    // B[0..15] = bxh,byh,bzh, bxl,byl,bzl, bxh,byh,bzh, one,one, sh,sl, bxl,byl,bzl
    uint4* B4 = (uint4*)(bfr + (size_t)idx * 16);
    B4[0] = make_uint4(pk(bxh,byh), pk(bzh,bxl), pk(byl,bzl), pk(bxh,byh));
    B4[1] = make_uint4(pk(bzh,one), pk(one,sh), pk(sl,bxl), pk(byl,bzl));
}

// Finalize tail, OUT-OF-LINE so the hot loop's register allocation is not
// perturbed (R15 lesson: inlining this collapsed the kernel to 60 VGPR).
// Runs on ONE wave, LDS-free: lane l sums rows l, l+64, l+128, l+192 of the
// 256-row chunk (reads via no-op atomicMin = device-coherent), shuffle-
// reduces, lane 0 adds the scaled partial to out.
__device__ __attribute__((noinline))
void finalize_tail(unsigned int* rowbase, float* out, float scale, int lane) {
    float d = 0.0f;
#pragma unroll
    for (int k = 0; k < 4; ++k) {
        unsigned v = atomicMin(&rowbase[lane + k * 64], 0x7F7F7F7Fu);
        d += sqrtf(__uint_as_float(v));
    }
#pragma unroll
    for (int off = 32; off >= 1; off >>= 1)
        d += __shfl_down(d, off, 64);
    if (lane == 0) atomicAdd(out, d * scale);
}

// Kernel 2: R17 chamfer loop byte-identical; epilogue atomicMin combine;
// then a done-counter tail (wave 0 only, no LDS) fires the out-of-line
// finalize for the last of the 4 x-blocks per (pair, 256-row chunk).
__global__ __launch_bounds__(BLK, 4)
void chamfer_kernel(const unsigned short* __restrict__ afr,
                    const unsigned short* __restrict__ bfr,
                    unsigned int* __restrict__ minbuf,
                    unsigned int* __restrict__ done,
                    float* __restrict__ out, int N, float scale) {
    __shared__ short8 sbuf[CHUNK * 2];            // 32 KB: [hi x1024][lo x1024]
    const int p  = blockIdx.z;
    const int pi = (p < 3) ? 0 : ((p < 5) ? 1 : 2);
    const int pj = (p < 3) ? (p + 1) : ((p < 5) ? (p - 1) : 3);
    const int tid  = threadIdx.x;
    const int w    = tid >> 6;
    const int l    = tid & 63;
    const int col  = l & 31;
    const int half = l >> 5;

    const int abase = (blockIdx.y * 4 + w) * 64;  // 64 a-rows per wave
    const int b0    = blockIdx.x * QTILE;

    const short8* aptr =
        (const short8*)(afr + ((size_t)pi * N + abase + col) * 16 + half * 8);
    const short8 A0 = aptr[0];
    const short8 A1 = aptr[64];                   // +32 points

    const char* gq = (const char*)(bfr + ((size_t)pj * N + b0) * 16);

    f32x16 m0, m1, zz;
#pragma unroll
    for (int i = 0; i < 16; ++i) { m0[i] = 3.402823466e38f; m1[i] = 3.402823466e38f; zz[i] = 0.0f; }

    for (int c = 0; c < QTILE / CHUNK; ++c) {
        __syncthreads();                          // previous phase fully consumed
        const char* gc = gq + (size_t)c * CHUNK * 32;
#pragma unroll
        for (int it = 0; it < (CHUNK * 32) / (BLK * 16); ++it) {   // 8 iters
            int i = it * BLK + tid;               // 0..2047 linear LDS slot
            const char* src = (i < CHUNK) ? (gc + (size_t)i * 32)
                                          : (gc + (size_t)(i - CHUNK) * 32 + 16);
            __builtin_amdgcn_global_load_lds(
                (const __attribute__((address_space(1))) unsigned int*)src,
                (__attribute__((address_space(3))) unsigned int*)(sbuf + i),
                16, 0, 0);
        }
        __syncthreads();                          // drains vmcnt, data visible

        const short8* bsel = half ? (sbuf + CHUNK) : sbuf;
        for (int t = 0; t < CHUNK / 32; t += 2) { // 2 b-tiles per iteration
            short8 B0 = bsel[t * 32 + col];
            short8 B1 = bsel[(t + 1) * 32 + col];
            __builtin_amdgcn_s_setprio(1);
            f32x16 d0 = __builtin_amdgcn_mfma_f32_32x32x16_bf16(A0, B0, zz, 0, 0, 0);
            f32x16 d1 = __builtin_amdgcn_mfma_f32_32x32x16_bf16(A0, B1, zz, 0, 0, 0);
            __builtin_amdgcn_s_setprio(0);
#pragma unroll
            for (int i = 0; i < 16; ++i)          // fminf only -> v_min3 fusion
                m0[i] = fminf(m0[i], fminf(d0[i], d1[i]));
            __builtin_amdgcn_s_setprio(1);
            d0 = __builtin_amdgcn_mfma_f32_32x32x16_bf16(A1, B0, zz, 0, 0, 0);
            d1 = __builtin_amdgcn_mfma_f32_32x32x16_bf16(A1, B1, zz, 0, 0, 0);
            __builtin_amdgcn_s_setprio(0);
#pragma unroll
            for (int i = 0; i < 16; ++i)
                m1[i] = fminf(m1[i], fminf(d0[i], d1[i]));
        }
    }

    // ---- epilogue: butterfly min across the 32 lanes of each half ----
#pragma unroll
    for (int off = 1; off <= 16; off <<= 1) {
#pragma unroll
        for (int i = 0; i < 16; ++i) {
            m0[i] = fminf(m0[i], __shfl_xor(m0[i], off, 64));
            m1[i] = fminf(m1[i], __shfl_xor(m1[i], off, 64));
        }
    }
    unsigned int* mb = minbuf + (size_t)p * N;
    if (col == 0) {
#pragma unroll
        for (int r = 0; r < 16; ++r) {
            int row = (r & 3) + 8 * (r >> 2) + 4 * half;   // verified C/D mapping
            atomicMin(&mb[abase + row],
                      __float_as_uint(fmaxf(m0[r], 0.0f)));
            atomicMin(&mb[abase + 32 + row],
                      __float_as_uint(fmaxf(m1[r], 0.0f)));
        }
    }

    // ---- fused finalize (wave 0 only, LDS-free, out-of-line) ----
    __threadfence();                              // mins visible before count
    __syncthreads();                              // all waves' mins issued
    if (w == 0) {
        unsigned old = 0;
        if (l == 0) old = atomicAdd(&done[p * 32 + blockIdx.y], 1u);
        old = __shfl(old, 0, 64);                 // wave-uniform
        if (old == 0x7F7F7F7Fu + 3u)              // done was memset to 0x7F
            finalize_tail(mb + blockIdx.y * 256, out, scale, l);
    }
}

extern "C" void kernel_launch(void* const* d_in, const int* in_sizes, int n_in,
                              void* d_out, int out_size, void* d_ws, size_t ws_size,
                              hipStream_t stream) {
    const float* points = (const float*)d_in[0];   // V x N x 3 fp32
    const float* poses  = (const float*)d_in[1];   // V x 4 x 4 fp32
    float* out = (float*)d_out;                    // scalar fp32

    const int N = in_sizes[0] / (VNUM * 3);        // 8192

    // ws: afr (1MB) | bfr (1MB) | minbuf uint[6*N] (192KB) | done uint[192]
    unsigned short* afr = (unsigned short*)d_ws;
    unsigned short* bfr = afr + (size_t)VNUM * N * 16;
    unsigned int* minbuf = (unsigned int*)(bfr + (size_t)VNUM * N * 16);
    unsigned int* done   = minbuf + (size_t)NPAIRS * N;

    // 0x7F fill: minbuf -> 0x7F7F7F7F (~3.39e38 > any d^2); done -> count base
    hipMemsetAsync(minbuf, 0x7F, ((size_t)NPAIRS * N + NPAIRS * 32) * 4, stream);
    hipMemsetAsync(out, 0, sizeof(float), stream);

    setup_kernel<<<(VNUM * N + BLK - 1) / BLK, BLK, 0, stream>>>(
        points, poses, afr, bfr, N);

    dim3 grid(N / QTILE, N / 256, NPAIRS);         // 4 x 32 x 6 = 768 blocks
    chamfer_kernel<<<grid, BLK, 0, stream>>>(afr, bfr, minbuf, done, out, N,
                                             1.0f / (6.0f * (float)N));
}

// Round 19
// 31.728 us; speedup vs baseline: 2.2952x; 2.2952x over previous
//
#include <hip/hip_runtime.h>
#include <math.h>

// V=4 views, N=8192 points, 6 directed chamfer terms (pair p rows=view pi, min over view pj)
#define VNUM   4
#define NPAIRS 6
#define BLK    256
#define QTILE  2048   // b-points per block (quarter of N)
#define CHUNK  1024   // b-points staged per LDS phase (32 KB)

using short8  = __attribute__((ext_vector_type(8)))  short;
using f32x16  = __attribute__((ext_vector_type(16))) float;

__device__ inline unsigned short f2bf(float x) {           // RNE to bf16
    unsigned u = __float_as_uint(x);
    return (unsigned short)((u + 0x7FFFu + ((u >> 16) & 1u)) >> 16);
}
__device__ inline float bf2f(unsigned short b) {
    return __uint_as_float(((unsigned)b) << 16);
}
__device__ inline unsigned pk(unsigned short lo, unsigned short hi) {
    return (unsigned)lo | ((unsigned)hi << 16);
}

// Kernel 1: world-transform, build K=16 bf16 fragments so that
// dot(Afrag[a], Bfrag[b]) = |a|^2 + |b|^2 - 2*(a_hi+a_lo).(b_hi+b_lo).
// Fragment stores vectorized to 2 x uint4 per array.
__global__ void setup_kernel(const float* __restrict__ pts,
                             const float* __restrict__ poses,
                             unsigned short* __restrict__ afr,
                             unsigned short* __restrict__ bfr,
                             unsigned int* __restrict__ minbuf,
                             float* __restrict__ out, int N) {
    int idx = blockIdx.x * blockDim.x + threadIdx.x;
    if (idx < NPAIRS * N) minbuf[idx] = 0x7F7FFFFFu;       // FLT_MAX bits
    if (idx == 0) *out = 0.0f;
    if (idx < VNUM * N) {
        int v = idx / N;
        const float* P = poses + v * 16;                   // row-major 4x4
        float px = pts[idx*3+0], py = pts[idx*3+1], pz = pts[idx*3+2];
        float x = fmaf(P[0], px, fmaf(P[1], py, fmaf(P[2],  pz, P[3])));
        float y = fmaf(P[4], px, fmaf(P[5], py, fmaf(P[6],  pz, P[7])));
        float z = fmaf(P[8], px, fmaf(P[9], py, fmaf(P[10], pz, P[11])));
        float s = fmaf(x, x, fmaf(y, y, z * z));
        unsigned short xh = f2bf(x), yh = f2bf(y), zh = f2bf(z);
        unsigned short xl = f2bf(x - bf2f(xh));
        unsigned short yl = f2bf(y - bf2f(yh));
        unsigned short zl = f2bf(z - bf2f(zh));
        unsigned short sh = f2bf(s), sl = f2bf(s - bf2f(sh));
        const unsigned short one = 0x3F80u;
        // -2 * bf16 is exact (power-of-two scale)
        unsigned short bxh = f2bf(-2.0f * bf2f(xh)), byh = f2bf(-2.0f * bf2f(yh)),
                       bzh = f2bf(-2.0f * bf2f(zh));
        unsigned short bxl = f2bf(-2.0f * bf2f(xl)), byl = f2bf(-2.0f * bf2f(yl)),
                       bzl = f2bf(-2.0f * bf2f(zl));
        // A[0..15] = xh,yh,zh, xh,yh,zh, xl,yl,zl, sh,sl, one,one, xl,yl,zl
        uint4* A4 = (uint4*)(afr + (size_t)idx * 16);
        A4[0] = make_uint4(pk(xh,yh), pk(zh,xh), pk(yh,zh), pk(xl,yl));
        A4[1] = make_uint4(pk(zl,sh), pk(sl,one), pk(one,xl), pk(yl,zl));
        // B[0..15] = bxh,byh,bzh, bxl,byl,bzl, bxh,byh,bzh, one,one, sh,sl, bxl,byl,bzl
        uint4* B4 = (uint4*)(bfr + (size_t)idx * 16);
        B4[0] = make_uint4(pk(bxh,byh), pk(bzh,bxl), pk(byl,bzl), pk(bxh,byh));
        B4[1] = make_uint4(pk(bzh,one), pk(one,sh), pk(sl,bxl), pk(byl,bzl));
    }
}

// Kernel 2: R17 byte-identical EXCEPT the s_setprio pair is removed
// (clean single-variable A/B; m190: setprio is negative on lockstep MFMA
// loops). Hard-coded HW-verified C/D mapping (col=lane&31,
// row=(reg&3)+8*(reg>>2)+4*(lane>>5)). Plain fminf only on MFMA outputs.
__global__ __launch_bounds__(BLK, 4)
void chamfer_kernel(const unsigned short* __restrict__ afr,
                    const unsigned short* __restrict__ bfr,
                    unsigned int* __restrict__ minbuf, int N) {
    __shared__ short8 sbuf[CHUNK * 2];            // 32 KB: [hi x1024][lo x1024]
    const int p  = blockIdx.z;
    const int pi = (p < 3) ? 0 : ((p < 5) ? 1 : 2);
    const int pj = (p < 3) ? (p + 1) : ((p < 5) ? (p - 1) : 3);
    const int tid  = threadIdx.x;
    const int w    = tid >> 6;
    const int l    = tid & 63;
    const int col  = l & 31;
    const int half = l >> 5;

    const int abase = (blockIdx.y * 4 + w) * 64;  // 64 a-rows per wave
    const int b0    = blockIdx.x * QTILE;

    const short8* aptr =
        (const short8*)(afr + ((size_t)pi * N + abase + col) * 16 + half * 8);
    const short8 A0 = aptr[0];
    const short8 A1 = aptr[64];                   // +32 points

    const char* gq = (const char*)(bfr + ((size_t)pj * N + b0) * 16);

    f32x16 m0, m1, zz;
#pragma unroll
    for (int i = 0; i < 16; ++i) { m0[i] = 3.402823466e38f; m1[i] = 3.402823466e38f; zz[i] = 0.0f; }

    for (int c = 0; c < QTILE / CHUNK; ++c) {
        __syncthreads();                          // previous phase fully consumed
        const char* gc = gq + (size_t)c * CHUNK * 32;
#pragma unroll
        for (int it = 0; it < (CHUNK * 32) / (BLK * 16); ++it) {   // 8 iters
            int i = it * BLK + tid;               // 0..2047 linear LDS slot
            const char* src = (i < CHUNK) ? (gc + (size_t)i * 32)
                                          : (gc + (size_t)(i - CHUNK) * 32 + 16);
            __builtin_amdgcn_global_load_lds(
                (const __attribute__((address_space(1))) unsigned int*)src,
                (__attribute__((address_space(3))) unsigned int*)(sbuf + i),
                16, 0, 0);
        }
        __syncthreads();                          // drains vmcnt, data visible

        const short8* bsel = half ? (sbuf + CHUNK) : sbuf;
        for (int t = 0; t < CHUNK / 32; t += 2) { // 2 b-tiles per iteration
            short8 B0 = bsel[t * 32 + col];
            short8 B1 = bsel[(t + 1) * 32 + col];
            f32x16 d0 = __builtin_amdgcn_mfma_f32_32x32x16_bf16(A0, B0, zz, 0, 0, 0);
            f32x16 d1 = __builtin_amdgcn_mfma_f32_32x32x16_bf16(A0, B1, zz, 0, 0, 0);
#pragma unroll
            for (int i = 0; i < 16; ++i)          // fminf only -> v_min3 fusion
                m0[i] = fminf(m0[i], fminf(d0[i], d1[i]));
            d0 = __builtin_amdgcn_mfma_f32_32x32x16_bf16(A1, B0, zz, 0, 0, 0);
            d1 = __builtin_amdgcn_mfma_f32_32x32x16_bf16(A1, B1, zz, 0, 0, 0);
#pragma unroll
            for (int i = 0; i < 16; ++i)
                m1[i] = fminf(m1[i], fminf(d0[i], d1[i]));
        }
    }

    // ---- epilogue: butterfly min across the 32 lanes of each half ----
#pragma unroll
    for (int off = 1; off <= 16; off <<= 1) {
#pragma unroll
        for (int i = 0; i < 16; ++i) {
            m0[i] = fminf(m0[i], __shfl_xor(m0[i], off, 64));
            m1[i] = fminf(m1[i], __shfl_xor(m1[i], off, 64));
        }
    }
    if (col == 0) {
        unsigned int* mb = minbuf + (size_t)p * N;
#pragma unroll
        for (int r = 0; r < 16; ++r) {
            int row = (r & 3) + 8 * (r >> 2) + 4 * half;   // verified C/D mapping
            atomicMin(&mb[abase + row],
                      __float_as_uint(fmaxf(m0[r], 0.0f)));
            atomicMin(&mb[abase + 32 + row],
                      __float_as_uint(fmaxf(m1[r], 0.0f)));
        }
    }
}

// Kernel 3: d = sqrt(min d^2), block-reduce, scaled atomicAdd into scalar out.
__global__ void finalize_kernel(const unsigned int* __restrict__ minbuf,
                                float* __restrict__ out, float scale) {
    __shared__ float red[BLK / 64];
    int idx = blockIdx.x * blockDim.x + threadIdx.x;
    float d = sqrtf(__uint_as_float(minbuf[idx]));
#pragma unroll
    for (int off = 32; off >= 1; off >>= 1)
        d += __shfl_down(d, off, 64);
    int lane = threadIdx.x & 63;
    int wid  = threadIdx.x >> 6;
    if (lane == 0) red[wid] = d;
    __syncthreads();
    if (threadIdx.x == 0) {
        float s = 0.0f;
#pragma unroll
        for (int wv = 0; wv < BLK / 64; ++wv) s += red[wv];
        atomicAdd(out, s * scale);
    }
}

extern "C" void kernel_launch(void* const* d_in, const int* in_sizes, int n_in,
                              void* d_out, int out_size, void* d_ws, size_t ws_size,
                              hipStream_t stream) {
    const float* points = (const float*)d_in[0];   // V x N x 3 fp32
    const float* poses  = (const float*)d_in[1];   // V x 4 x 4 fp32
    float* out = (float*)d_out;                    // scalar fp32

    const int N = in_sizes[0] / (VNUM * 3);        // 8192

    // ws: afr (V*N*16 bf16 = 1MB) | bfr (1MB) | minbuf (6*N uint = 192KB)
    unsigned short* afr = (unsigned short*)d_ws;
    unsigned short* bfr = afr + (size_t)VNUM * N * 16;
    unsigned int* minbuf = (unsigned int*)(bfr + (size_t)VNUM * N * 16);

    int setup_threads = NPAIRS * N;
    setup_kernel<<<(setup_threads + BLK - 1) / BLK, BLK, 0, stream>>>(
        points, poses, afr, bfr, minbuf, out, N);

    dim3 grid(N / QTILE, N / 256, NPAIRS);         // 4 x 32 x 6 = 768 blocks
    chamfer_kernel<<<grid, BLK, 0, stream>>>(afr, bfr, minbuf, N);

    finalize_kernel<<<(NPAIRS * N) / BLK, BLK, 0, stream>>>(
        minbuf, out, 1.0f / (6.0f * (float)N));
}